// Round 9
// baseline (3133.984 us; speedup 1.0000x reference)
//
#include <hip/hip_runtime.h>
#include <hip/hip_bf16.h>

#define HDIM 32
#define NL 8
#define NBATCH 256
#define TLEN 4096
#define NTHR 512
#define KSUP 8
#define NSUP (TLEN / KSUP)   // 512 active supersteps per wave
#define NST (NSUP + NL)      // 520 supersteps total (fill/drain)

typedef __attribute__((ext_vector_type(8))) unsigned short u16x8;

__device__ __forceinline__ float bf2f(unsigned short u) {
  union { unsigned int i; float f; } v;
  v.i = ((unsigned int)u) << 16;
  return v.f;
}

__device__ __forceinline__ float fast_tanh(float x) {
  // tanh(x) = 1 - 2/(exp(2x)+1); exp(2x) = 2^(x * 2/ln2)
  float e2 = exp2f(x * 2.8853900817779268f);
#if __has_builtin(__builtin_amdgcn_rcpf)
  float r = __builtin_amdgcn_rcpf(e2 + 1.0f);
#else
  float r = 1.0f / (e2 + 1.0f);
#endif
  return 1.0f - 2.0f * r;
}

// Cross-half combine p[i] + p[i^32] on the VALU pipe (permlane32_swap).
__device__ __forceinline__ float combine_halves(float p) {
#if __has_builtin(__builtin_amdgcn_permlane32_swap)
  typedef __attribute__((ext_vector_type(2))) int i32x2;
  i32x2 r = __builtin_amdgcn_permlane32_swap(
      __float_as_int(p), __float_as_int(p), false, false);
  return __int_as_float(r.x) + __int_as_float(r.y);
#else
  return p + __shfl_xor(p, 32, 64);
#endif
}

template <bool BF16>
__device__ __forceinline__ float ld1(const void* p, int off) {
  return BF16 ? bf2f(((const unsigned short*)p)[off]) : ((const float*)p)[off];
}

// load 16 contiguous elements, widened to fp32
template <bool BF16>
__device__ __forceinline__ void ld16(const void* p, int elem_off, float* dst) {
  if (BF16) {
    const u16x8* wp = (const u16x8*)((const unsigned short*)p + elem_off);
#pragma unroll
    for (int m = 0; m < 2; ++m) {
      u16x8 v = wp[m];
#pragma unroll
      for (int e = 0; e < 8; ++e) dst[m * 8 + e] = bf2f(v[e]);
    }
  } else {
    const float4* wp = (const float4*)((const float*)p + elem_off);
#pragma unroll
    for (int m = 0; m < 4; ++m) {
      float4 v = wp[m];
      dst[m * 4 + 0] = v.x; dst[m * 4 + 1] = v.y;
      dst[m * 4 + 2] = v.z; dst[m * 4 + 3] = v.w;
    }
  }
}

// 16-MAC dot of register weights against 16 LDS floats (4x ds_read_b128)
__device__ __forceinline__ float dot16(const float* w, const float4* y,
                                       float init) {
  float a0 = init, a1 = 0.0f;
#pragma unroll
  for (int q = 0; q < 4; ++q) {
    const float4 v = y[q];
    a0 = fmaf(w[4 * q + 0], v.x, a0);
    a1 = fmaf(w[4 * q + 1], v.y, a1);
    a0 = fmaf(w[4 * q + 2], v.z, a0);
    a1 = fmaf(w[4 * q + 3], v.w, a1);
  }
  return a0 + a1;
}

// 8-layer RNN stack, superstep-pipelined (k=8): wave = layer l; at superstep
// s, wave l computes t in [8(s-l), 8(s-l)+8). Cross-wave handoff via ybuf
// (double-buffered by superstep parity) + ONE barrier per superstep.
// Recurrence chain (within-wave): state h_j lives in lane j's VGPR (both
// k-halves duplicate it). Per substep, the 32 h values are broadcast to all
// lanes via v_readlane -> SGPR (VALU pipe, no LDS on the chain!), and each
// lane runs the FULL 32-MAC hh dot with SGPR h-operands -> tanh -> new h.
// No cross-lane combine, no LDS round-trip on the chain. ih-partials are
// h-independent: split-K dot16 + permlane combine, hoisted per superstep.
// The ybuf ds_write (kh=0 lanes) is only consumed after __syncthreads.
// fc dot: wave l handles sub-timestep i=l of the previous superstep's
// top-layer block -> mid[] (LDS). No global memory ops in the loop.
// NOTE: seq and mid may ALIAS (stack 2) — no __restrict__ on them.
template <bool BF16>
__device__ __forceinline__ void run_stack(
    int tid, int l, int j, int kh, int koff,
    const void* __restrict__ Wih0, const void* __restrict__ Wih,
    const void* __restrict__ Whh,  const void* __restrict__ bih,
    const void* __restrict__ bhh,  const void* __restrict__ fcW,
    const void* __restrict__ fcb,
    const float* seq, float* mid,
    float (&ybuf)[2][NL][KSUP][HDIM],
    float& hreg)
{
  float whh[HDIM], wih[16], fcd[16];
  float w0 = 0.0f, bias = 0.0f, fcbias = 0.0f;
  ld16<BF16>(Whh, (l * HDIM + j) * HDIM, whh);
  ld16<BF16>(Whh, (l * HDIM + j) * HDIM + 16, whh + 16);
  if (l > 0) {
    ld16<BF16>(Wih, ((l - 1) * HDIM + j) * HDIM + koff, wih);
    // bias enters via the kh=0 partial only (summed once by the combine)
    if (kh == 0)
      bias = ld1<BF16>(bih, l * HDIM + j) + ld1<BF16>(bhh, l * HDIM + j);
  } else {
#pragma unroll
    for (int i = 0; i < 16; ++i) wih[i] = 0.0f;
    // layer 0: scalar input; identical on both halves (no combine needed)
    w0 = ld1<BF16>(Wih0, j);
    bias = ld1<BF16>(bih, l * HDIM + j) + ld1<BF16>(bhh, l * HDIM + j);
  }
  ld16<BF16>(fcW, koff, fcd);
  fcbias = ld1<BF16>(fcb, 0);

#pragma unroll 2
  for (int s = 0; s < NST; ++s) {
    const int rb = (s & 1) ^ 1;   // read: written by others at superstep s-1
    const int wb = s & 1;         // write: read by others at superstep s+1
    // ---- fc dot: wave l handles sub-timestep i=l of block sf (off-chain) --
    {
      const unsigned sf = (unsigned)(s - NL);
      if (sf < (unsigned)NSUP) {
        float f = dot16(fcd, (const float4*)&ybuf[rb][NL - 1][l][koff], 0.0f);
        f = combine_halves(f);
        if ((tid & 63) == 0) mid[((int)sf << 3) + l] = f + fcbias;
      }
    }
    // ---- own layer's 8 timesteps ----
    const unsigned sa = (unsigned)(s - l);
    if (sa < (unsigned)NSUP) {
      const int t0 = (int)sa << 3;
      float e[KSUP];                     // h-independent ih inputs (hoisted)
      if (l == 0) {
#pragma unroll
        for (int i = 0; i < KSUP; ++i) e[i] = fmaf(w0, seq[t0 + i], bias);
      } else {
#pragma unroll
        for (int i = 0; i < KSUP; ++i) {
          float ep = dot16(wih, (const float4*)&ybuf[rb][l - 1][i][koff], bias);
          e[i] = combine_halves(ep);     // full ih dot + bias, off-chain
        }
      }
#pragma unroll
      for (int i = 0; i < KSUP; ++i) {
        // broadcast current state (lane k holds h_k) to SGPRs; full 32-MAC
        // hh dot per lane with SGPR h-operands — no LDS on the chain.
        const int hbits = __float_as_int(hreg);
        float a0 = e[i], a1 = 0.0f, a2 = 0.0f, a3 = 0.0f;
#pragma unroll
        for (int q = 0; q < 8; ++q) {
          const float h0b = __int_as_float(__builtin_amdgcn_readlane(hbits, 4 * q + 0));
          const float h1b = __int_as_float(__builtin_amdgcn_readlane(hbits, 4 * q + 1));
          const float h2b = __int_as_float(__builtin_amdgcn_readlane(hbits, 4 * q + 2));
          const float h3b = __int_as_float(__builtin_amdgcn_readlane(hbits, 4 * q + 3));
          a0 = fmaf(whh[4 * q + 0], h0b, a0);
          a1 = fmaf(whh[4 * q + 1], h1b, a1);
          a2 = fmaf(whh[4 * q + 2], h2b, a2);
          a3 = fmaf(whh[4 * q + 3], h3b, a3);
        }
        const float h = fast_tanh((a0 + a1) + (a2 + a3));
        hreg = h;
        if (kh == 0) ybuf[wb][l][i][j] = h;  // cross-wave handoff (off-chain)
      }
    }
    __syncthreads();                     // one barrier per 8 timesteps
  }
}

// Dtype probe: bf16-packed N(0,1) concentrates the low-half exponent field
// in [112,132]; fp32 low bits are ~uniform mantissa (~8% hit rate).
__global__ void detect_dtype_kernel(const unsigned int* __restrict__ xu,
                                    int* __restrict__ flag) {
  const int tid = threadIdx.x;
  unsigned int lo = xu[tid] & 0xFFFFu;
  int e = (int)((lo >> 7) & 0xFFu);
  int cnt = __syncthreads_count((e >= 112 && e <= 132) ? 1 : 0);
  if (tid == 0) *flag = (cnt > 128) ? 1 : 0;
}

template <bool BF16>
__global__ __launch_bounds__(NTHR) void radar_rnn_kernel(
    const int* __restrict__ flag,
    const void* __restrict__ x,
    const void* __restrict__ h0,
    const void* __restrict__ W1ih0, const void* __restrict__ W1ih,
    const void* __restrict__ W1hh,  const void* __restrict__ b1ih,
    const void* __restrict__ b1hh,  const void* __restrict__ fc1W,
    const void* __restrict__ fc1b,
    const void* __restrict__ W2ih0, const void* __restrict__ W2ih,
    const void* __restrict__ W2hh,  const void* __restrict__ b2ih,
    const void* __restrict__ b2hh,  const void* __restrict__ outW,
    const void* __restrict__ outb,
    void* __restrict__ out)
{
  if (*flag != (BF16 ? 1 : 0)) return;

  __shared__ __align__(16) float seq[TLEN];     // stack-1 input scalars
  __shared__ __align__(16) float midbuf[TLEN];  // fc1 out = stack-2 in = y
  __shared__ __align__(16) float ybuf[2][NL][KSUP][HDIM];

  const int tid = threadIdx.x;
  const int b = blockIdx.x;
  const int l = tid >> 6;          // wave = layer
  const int lane = tid & 63;
  const int j = lane & 31;         // output row
  const int kh = lane >> 5;        // k-half (split-K 2, for ih/fc dots)
  const int koff = kh << 4;

  // stage x[b,:] into LDS as fp32
  if (BF16) {
    const u16x8* xv = (const u16x8*)((const unsigned short*)x + (size_t)b * TLEN);
    for (int i = tid; i < TLEN / 8; i += NTHR) {
      u16x8 v = xv[i];
#pragma unroll
      for (int e = 0; e < 8; ++e) seq[i * 8 + e] = bf2f(v[e]);
    }
  } else {
    const float4* xv = (const float4*)((const float*)x + (size_t)b * TLEN);
    for (int i = tid; i < TLEN / 4; i += NTHR) {
      float4 v = xv[i];
      seq[i * 4 + 0] = v.x; seq[i * 4 + 1] = v.y;
      seq[i * 4 + 2] = v.z; seq[i * 4 + 3] = v.w;
    }
  }

  // state: lane (j, kh) holds h_j of its layer (duplicated across halves)
  float hreg = ld1<BF16>(h0, (l * NBATCH + b) * HDIM + j);
  __syncthreads();

  // stack 1: seq -> fc1 results in midbuf; hreg ends as h1[l,b,j]
  run_stack<BF16>(tid, l, j, kh, koff, W1ih0, W1ih, W1hh, b1ih, b1hh,
                  fc1W, fc1b, seq, midbuf, ybuf, hreg);
  // stack 2: midbuf as input (h1 carried in hreg); out-fc results overwrite
  // consumed midbuf slots (write trails all readers by >= 1 superstep)
  run_stack<BF16>(tid, l, j, kh, koff, W2ih0, W2ih, W2hh, b2ih, b2hh,
                  outW, outb, midbuf, midbuf, ybuf, hreg);

  // flush y (midbuf) to global, coalesced (loop ended with a barrier)
  if (BF16) {
    __hip_bfloat16* o = (__hip_bfloat16*)out + (size_t)b * TLEN;
    for (int i = tid; i < TLEN; i += NTHR) o[i] = __float2bfloat16(midbuf[i]);
  } else {
    float* o = (float*)out + (size_t)b * TLEN;
    for (int i = tid; i < TLEN; i += NTHR) o[i] = midbuf[i];
  }
  // final hidden states h2: [L, B, H]
  if (!kh) {
    const size_t hidx =
        (size_t)NBATCH * TLEN + (size_t)(l * NBATCH + b) * HDIM + j;
    if (BF16)
      ((__hip_bfloat16*)out)[hidx] = __float2bfloat16(hreg);
    else
      ((float*)out)[hidx] = hreg;
  }
}

extern "C" void kernel_launch(void* const* d_in, const int* in_sizes, int n_in,
                              void* d_out, int out_size, void* d_ws, size_t ws_size,
                              hipStream_t stream) {
  int* flag = (int*)d_ws;
  detect_dtype_kernel<<<dim3(1), dim3(256), 0, stream>>>(
      (const unsigned int*)d_in[0], flag);

  radar_rnn_kernel<true><<<dim3(NBATCH), dim3(NTHR), 0, stream>>>(
      flag, d_in[0], d_in[1], d_in[2], d_in[3], d_in[4], d_in[5], d_in[6],
      d_in[7], d_in[8], d_in[9], d_in[10], d_in[11], d_in[12], d_in[13],
      d_in[14], d_in[15], d_out);
  radar_rnn_kernel<false><<<dim3(NBATCH), dim3(NTHR), 0, stream>>>(
      flag, d_in[0], d_in[1], d_in[2], d_in[3], d_in[4], d_in[5], d_in[6],
      d_in[7], d_in[8], d_in[9], d_in[10], d_in[11], d_in[12], d_in[13],
      d_in[14], d_in[15], d_out);
}

// Round 10
// 1952.263 us; speedup vs baseline: 1.6053x; 1.6053x over previous
//
#include <hip/hip_runtime.h>
#include <hip/hip_bf16.h>

#define HDIM 32
#define NL 8
#define NBATCH 256
#define TLEN 4096
#define NTHR 512
#define KSUP 8
#define NSUP (TLEN / KSUP)   // 512 active supersteps per wave
#define NST (NSUP + NL)      // 520 supersteps total (fill/drain)

typedef __attribute__((ext_vector_type(8))) unsigned short u16x8;
typedef __attribute__((ext_vector_type(2))) float f32x2;

__device__ __forceinline__ float bf2f(unsigned short u) {
  union { unsigned int i; float f; } v;
  v.i = ((unsigned int)u) << 16;
  return v.f;
}

__device__ __forceinline__ float fast_tanh(float x) {
  // tanh(x) = 1 - 2/(exp(2x)+1); exp(2x) = 2^(x * 2/ln2)
  float e2 = exp2f(x * 2.8853900817779268f);
#if __has_builtin(__builtin_amdgcn_rcpf)
  float r = __builtin_amdgcn_rcpf(e2 + 1.0f);
#else
  float r = 1.0f / (e2 + 1.0f);
#endif
  return 1.0f - 2.0f * r;
}

// Cross-half combine p[i] + p[i^32] on the VALU pipe (permlane32_swap).
__device__ __forceinline__ float combine_halves(float p) {
#if __has_builtin(__builtin_amdgcn_permlane32_swap)
  typedef __attribute__((ext_vector_type(2))) int i32x2;
  i32x2 r = __builtin_amdgcn_permlane32_swap(
      __float_as_int(p), __float_as_int(p), false, false);
  return __int_as_float(r.x) + __int_as_float(r.y);
#else
  return p + __shfl_xor(p, 32, 64);
#endif
}

// packed 2xfp32 FMA -> v_pk_fma_f32 (full-rate on CDNA): halves dot issue
__device__ __forceinline__ f32x2 pkfma(f32x2 a, f32x2 b, f32x2 c) {
#if __has_builtin(__builtin_elementwise_fma)
  return __builtin_elementwise_fma(a, b, c);
#else
  f32x2 r; r.x = fmaf(a.x, b.x, c.x); r.y = fmaf(a.y, b.y, c.y); return r;
#endif
}

template <bool BF16>
__device__ __forceinline__ float ld1(const void* p, int off) {
  return BF16 ? bf2f(((const unsigned short*)p)[off]) : ((const float*)p)[off];
}

// load 16 contiguous elements, widened to fp32
template <bool BF16>
__device__ __forceinline__ void ld16(const void* p, int elem_off, float* dst) {
  if (BF16) {
    const u16x8* wp = (const u16x8*)((const unsigned short*)p + elem_off);
#pragma unroll
    for (int m = 0; m < 2; ++m) {
      u16x8 v = wp[m];
#pragma unroll
      for (int e = 0; e < 8; ++e) dst[m * 8 + e] = bf2f(v[e]);
    }
  } else {
    const float4* wp = (const float4*)((const float*)p + elem_off);
#pragma unroll
    for (int m = 0; m < 4; ++m) {
      float4 v = wp[m];
      dst[m * 4 + 0] = v.x; dst[m * 4 + 1] = v.y;
      dst[m * 4 + 2] = v.z; dst[m * 4 + 3] = v.w;
    }
  }
}

__device__ __forceinline__ void pack8(const float* t, f32x2* d) {
#pragma unroll
  for (int q = 0; q < 8; ++q) {
    f32x2 u; u.x = t[2 * q]; u.y = t[2 * q + 1]; d[q] = u;
  }
}

// 16-MAC half-dot via 8 pk_fma; acc.x/acc.y = R8's a0/a1 (same pairing ->
// value-identical). Returns the HALF sum (split-K halves combined later).
__device__ __forceinline__ float dot16pk(const f32x2* w, const float4* y,
                                         float init) {
  f32x2 acc; acc.x = init; acc.y = 0.0f;
#pragma unroll
  for (int q = 0; q < 4; ++q) {
    const float4 v = y[q];
    f32x2 v01; v01.x = v.x; v01.y = v.y;
    f32x2 v23; v23.x = v.z; v23.y = v.w;
    acc = pkfma(w[2 * q + 0], v01, acc);
    acc = pkfma(w[2 * q + 1], v23, acc);
  }
  return acc.x + acc.y;
}

// 8-layer RNN stack, superstep-pipelined (k=8): wave = layer l; at superstep
// s, wave l computes t in [8(s-l), 8(s-l)+8). Cross-wave handoff via ybuf
// (double-buffered by superstep parity) + ONE barrier per superstep.
// Split-K: lane (j,kh) holds half the Whh/Wih row; ih partial e and hh
// partial stay SPLIT; one permlane combine after the hh dot merges both.
// The ih partials are software-pipelined depth-1 (e[i+1] computed during
// substep i) so the in-order DS FIFO carries only ~9 ops per substep and the
// e-FMAs fill the chain stall (R8 hoisted all 32 e-reads up front -> FIFO
// backlog delayed every readback). fc dot moved AFTER the substep loop
// (ybuf[rb] stays valid until the barrier). All dots use v_pk_fma_f32.
// Same-wave DS ops complete in order (R6/R8-validated): the hvec readback
// needs no explicit waitcnt; sched_barrier(0x7) pins DS order, ALU may cross.
// NOTE: seq and mid may ALIAS (stack 2) — no __restrict__ on them.
template <bool BF16>
__device__ __forceinline__ void run_stack(
    int tid, int l, int j, int kh, int koff,
    const void* __restrict__ Wih0, const void* __restrict__ Wih,
    const void* __restrict__ Whh,  const void* __restrict__ bih,
    const void* __restrict__ bhh,  const void* __restrict__ fcW,
    const void* __restrict__ fcb,
    const float* seq, float* mid,
    float (&ybuf)[2][NL][KSUP][HDIM],
    f32x2 (&hv2)[8], float& hown)
{
  float tmp[16];
  f32x2 whh2[8], wih2[8], fcd2[8];
  float w0 = 0.0f, bias = 0.0f, fcbias = 0.0f;
  ld16<BF16>(Whh, (l * HDIM + j) * HDIM + koff, tmp);
  pack8(tmp, whh2);
  if (l > 0) {
    ld16<BF16>(Wih, ((l - 1) * HDIM + j) * HDIM + koff, tmp);
    pack8(tmp, wih2);
  } else {
#pragma unroll
    for (int q = 0; q < 8; ++q) { f32x2 z; z.x = 0.0f; z.y = 0.0f; wih2[q] = z; }
    if (kh == 0) w0 = ld1<BF16>(Wih0, j);   // kh=1 half contributes 0
  }
  // bias enters via the kh=0 partial only (merged by the single combine)
  if (kh == 0)
    bias = ld1<BF16>(bih, l * HDIM + j) + ld1<BF16>(bhh, l * HDIM + j);
  ld16<BF16>(fcW, koff, tmp);
  pack8(tmp, fcd2);
  fcbias = ld1<BF16>(fcb, 0);

#pragma unroll 2
  for (int s = 0; s < NST; ++s) {
    const int rb = (s & 1) ^ 1;   // read: written by others at superstep s-1
    const int wb = s & 1;         // write: read by others at superstep s+1
    // ---- own layer's 8 timesteps (e pipelined depth 1) ----
    const unsigned sa = (unsigned)(s - l);
    if (sa < (unsigned)NSUP) {
      const int t0 = (int)sa << 3;
      float ecur;
      if (l == 0)
        ecur = fmaf(w0, seq[t0], bias);
      else
        ecur = dot16pk(wih2, (const float4*)&ybuf[rb][l - 1][0][koff], bias);
#pragma unroll
      for (int i = 0; i < KSUP; ++i) {
        float enext = 0.0f;
        if (i + 1 < KSUP) {
          if (l == 0)
            enext = fmaf(w0, seq[t0 + i + 1], bias);
          else
            enext = dot16pk(wih2,
                            (const float4*)&ybuf[rb][l - 1][i + 1][koff], bias);
        }
        // hh half-dot on top of the (split) ih partial
        f32x2 acc; acc.x = ecur; acc.y = 0.0f;
#pragma unroll
        for (int q = 0; q < 8; ++q) acc = pkfma(whh2[q], hv2[q], acc);
        const float h = fast_tanh(combine_halves(acc.x + acc.y));
        hown = h;
        if (kh == 0) ybuf[wb][l][i][j] = h;  // handoff + next-substep state
        // Same-wave DS ops are in order: the readback observes the write
        // without an explicit wait (R6/R8-validated). 0x7: ALU may cross.
        __builtin_amdgcn_sched_barrier(0x7);
        const float4* hx = (const float4*)&ybuf[wb][l][i][koff];
#pragma unroll
        for (int q = 0; q < 4; ++q) {
          const float4 H = hx[q];
          f32x2 u; u.x = H.x; u.y = H.y; hv2[2 * q + 0] = u;
          f32x2 v; v.x = H.z; v.y = H.w; hv2[2 * q + 1] = v;
        }
        ecur = enext;
      }
    }
    // ---- fc dot AFTER substeps: wave l handles sub-timestep i=l of the
    // previous superstep's top-layer block (ybuf[rb] valid until barrier) ----
    {
      const unsigned sf = (unsigned)(s - NL);
      if (sf < (unsigned)NSUP) {
        float f = dot16pk(fcd2, (const float4*)&ybuf[rb][NL - 1][l][koff], 0.0f);
        f = combine_halves(f);
        if ((tid & 63) == 0) mid[((int)sf << 3) + l] = f + fcbias;
      }
    }
    __syncthreads();                     // one barrier per 8 timesteps
  }
}

// Dtype probe: bf16-packed N(0,1) concentrates the low-half exponent field
// in [112,132]; fp32 low bits are ~uniform mantissa (~8% hit rate).
__global__ void detect_dtype_kernel(const unsigned int* __restrict__ xu,
                                    int* __restrict__ flag) {
  const int tid = threadIdx.x;
  unsigned int lo = xu[tid] & 0xFFFFu;
  int e = (int)((lo >> 7) & 0xFFu);
  int cnt = __syncthreads_count((e >= 112 && e <= 132) ? 1 : 0);
  if (tid == 0) *flag = (cnt > 128) ? 1 : 0;
}

template <bool BF16>
__global__ __launch_bounds__(NTHR) void radar_rnn_kernel(
    const int* __restrict__ flag,
    const void* __restrict__ x,
    const void* __restrict__ h0,
    const void* __restrict__ W1ih0, const void* __restrict__ W1ih,
    const void* __restrict__ W1hh,  const void* __restrict__ b1ih,
    const void* __restrict__ b1hh,  const void* __restrict__ fc1W,
    const void* __restrict__ fc1b,
    const void* __restrict__ W2ih0, const void* __restrict__ W2ih,
    const void* __restrict__ W2hh,  const void* __restrict__ b2ih,
    const void* __restrict__ b2hh,  const void* __restrict__ outW,
    const void* __restrict__ outb,
    void* __restrict__ out)
{
  if (*flag != (BF16 ? 1 : 0)) return;

  __shared__ __align__(16) float seq[TLEN];     // stack-1 input scalars
  __shared__ __align__(16) float midbuf[TLEN];  // fc1 out = stack-2 in = y
  __shared__ __align__(16) float ybuf[2][NL][KSUP][HDIM];

  const int tid = threadIdx.x;
  const int b = blockIdx.x;
  const int l = tid >> 6;          // wave = layer
  const int lane = tid & 63;
  const int j = lane & 31;         // output row
  const int kh = lane >> 5;        // k-half (split-K 2)
  const int koff = kh << 4;

  // stage x[b,:] into LDS as fp32
  if (BF16) {
    const u16x8* xv = (const u16x8*)((const unsigned short*)x + (size_t)b * TLEN);
    for (int i = tid; i < TLEN / 8; i += NTHR) {
      u16x8 v = xv[i];
#pragma unroll
      for (int e = 0; e < 8; ++e) seq[i * 8 + e] = bf2f(v[e]);
    }
  } else {
    const float4* xv = (const float4*)((const float*)x + (size_t)b * TLEN);
    for (int i = tid; i < TLEN / 4; i += NTHR) {
      float4 v = xv[i];
      seq[i * 4 + 0] = v.x; seq[i * 4 + 1] = v.y;
      seq[i * 4 + 2] = v.z; seq[i * 4 + 3] = v.w;
    }
  }

  // distributed initial hidden state: lane (j,kh) holds h0[l,b,koff..koff+16)
  float tmp[16];
  f32x2 hv2[8];
  float hown = 0.0f;
  ld16<BF16>(h0, (l * NBATCH + b) * HDIM + koff, tmp);
  pack8(tmp, hv2);
  __syncthreads();

  // stack 1: seq -> fc1 results in midbuf; hv2/hown end as h1 (own half)
  run_stack<BF16>(tid, l, j, kh, koff, W1ih0, W1ih, W1hh, b1ih, b1hh,
                  fc1W, fc1b, seq, midbuf, ybuf, hv2, hown);
  // stack 2: midbuf as input (h1 carried in hv2); out-fc results overwrite
  // consumed midbuf slots (write trails all readers by >= 1 superstep)
  run_stack<BF16>(tid, l, j, kh, koff, W2ih0, W2ih, W2hh, b2ih, b2hh,
                  outW, outb, midbuf, midbuf, ybuf, hv2, hown);

  // flush y (midbuf) to global, coalesced (loop ended with a barrier)
  if (BF16) {
    __hip_bfloat16* o = (__hip_bfloat16*)out + (size_t)b * TLEN;
    for (int i = tid; i < TLEN; i += NTHR) o[i] = __float2bfloat16(midbuf[i]);
  } else {
    float* o = (float*)out + (size_t)b * TLEN;
    for (int i = tid; i < TLEN; i += NTHR) o[i] = midbuf[i];
  }
  // final hidden states h2: [L, B, H]
  if (!kh) {
    const size_t hidx =
        (size_t)NBATCH * TLEN + (size_t)(l * NBATCH + b) * HDIM + j;
    if (BF16)
      ((__hip_bfloat16*)out)[hidx] = __float2bfloat16(hown);
    else
      ((float*)out)[hidx] = hown;
  }
}

extern "C" void kernel_launch(void* const* d_in, const int* in_sizes, int n_in,
                              void* d_out, int out_size, void* d_ws, size_t ws_size,
                              hipStream_t stream) {
  int* flag = (int*)d_ws;
  detect_dtype_kernel<<<dim3(1), dim3(256), 0, stream>>>(
      (const unsigned int*)d_in[0], flag);

  radar_rnn_kernel<true><<<dim3(NBATCH), dim3(NTHR), 0, stream>>>(
      flag, d_in[0], d_in[1], d_in[2], d_in[3], d_in[4], d_in[5], d_in[6],
      d_in[7], d_in[8], d_in[9], d_in[10], d_in[11], d_in[12], d_in[13],
      d_in[14], d_in[15], d_out);
  radar_rnn_kernel<false><<<dim3(NBATCH), dim3(NTHR), 0, stream>>>(
      flag, d_in[0], d_in[1], d_in[2], d_in[3], d_in[4], d_in[5], d_in[6],
      d_in[7], d_in[8], d_in[9], d_in[10], d_in[11], d_in[12], d_in[13],
      d_in[14], d_in[15], d_out);
}